// Round 4
// baseline (102.411 us; speedup 1.0000x reference)
//
#include <hip/hip_runtime.h>
#include <stdint.h>

#define B  32
#define D  576
#define L  196
#define CC 10
#define K  256
#define M  (CC * K)   // 2560
#define SLOTS 64      // max selected literals per clause (P(Binom(576,.02)>64) ~ 1e-34)
#define NF4 49        // float4 chunks per 196-patch row
#define MT 64         // clause tile per block

#define PACK_BLOCKS ((B * D + 3) / 4)   // 4608 blocks, wave per (b,d)
#define CSR_BLOCKS  ((M + 3) / 4)       // 640 blocks, wave per clause

// ---------------------------------------------------------------------------
// Fused prologue. Blocks [0, PACK_BLOCKS): pack literals over the PATCH axis:
// litbits[(d*B + b)*4 + w], bit (l%64) of word (l/64) = (lit[b][d][l] > 0.5).
// Blocks [PACK_BLOCKS, +CSR_BLOCKS): CSR of selected literal indices/clause.
// ---------------------------------------------------------------------------
__global__ __launch_bounds__(256) void prologue_k(
    const float* __restrict__ lit, const int* __restrict__ mask,
    uint64_t* __restrict__ litbits, int* __restrict__ cnt,
    uint16_t* __restrict__ list) {
    const int lane = threadIdx.x & 63;
    const int wave = threadIdx.x >> 6;

    if (blockIdx.x < PACK_BLOCKS) {
        const int wid = blockIdx.x * 4 + wave;   // [0, B*D)
        if (wid >= B * D) return;
        const int b = wid % B;
        const int d = wid / B;
        const float* base = lit + ((size_t)b * D + d) * L;

        uint64_t w0 = __ballot(base[lane] > 0.5f);
        uint64_t w1 = __ballot(base[64 + lane] > 0.5f);
        uint64_t w2 = __ballot(base[128 + lane] > 0.5f);
        float tail = (lane < 4) ? base[192 + lane] : 0.0f;
        uint64_t w3 = __ballot(tail > 0.5f);

        uint64_t* out = litbits + ((size_t)d * B + b) * 4;
        if (lane == 0) { out[0] = w0; out[1] = w1; out[2] = w2; out[3] = w3; }
    } else {
        const int m = (blockIdx.x - PACK_BLOCKS) * 4 + wave;
        if (m >= M) return;
        const int* row = mask + (size_t)m * D;
        int base = 0;
#pragma unroll
        for (int r = 0; r < 9; ++r) {
            int d = r * 64 + lane;
            bool sel = (row[d] != 0);
            uint64_t bal = __ballot(sel);
            if (sel) {
                int pos = base + __popcll(bal & ((1ull << lane) - 1ull));
                if (pos < SLOTS) list[(size_t)m * SLOTS + pos] = (uint16_t)d;
            }
            base += __popcll(bal);
        }
        if (lane == 0) cnt[m] = (base < SLOTS) ? base : SLOTS;
    }
}

// ---------------------------------------------------------------------------
// Main v4: block (mt, b) owns batch b and 64 consecutive clauses m0..m0+63.
// 128 threads, 2 per clause (h splits the 4 patch-words). Gathers are
// L2-resident scattered 16B loads; the payoff is the store phase: the block's
// 3136 float4 stores cover ONE contiguous 50 KB span of cmap (perfect DRAM
// page locality), vs eval3's 64 rows scattered at 2 MB stride.
// Grid = 40 x 32 = 1280 = exactly 5 blocks/CU.
// ---------------------------------------------------------------------------
__global__ __launch_bounds__(128) void clause_eval4_k(
    const uint64_t* __restrict__ litbits, const int* __restrict__ cnt,
    const uint16_t* __restrict__ list, float* __restrict__ cmap,
    float* __restrict__ cor) {
    __shared__ uint64_t res[MT * 4];          // [clause][word]  2 KB
    __shared__ uint16_t sh_list[MT * SLOTS];  // 8 KB
    __shared__ int      sh_cnt[MT];           // 256 B

    const int t  = threadIdx.x;               // 0..127
    const int m0 = blockIdx.x * MT;
    const int b  = blockIdx.y;

    // stage clause lists (8 KB) + counts, coalesced 16B loads
    {
        const uint4* lp = (const uint4*)(list + (size_t)m0 * SLOTS);
        uint4* sp = (uint4*)sh_list;
#pragma unroll
        for (int i = t; i < MT * SLOTS * 2 / 16; i += 128) sp[i] = lp[i];
        if (t < MT) sh_cnt[t] = cnt[m0 + t];
    }
    __syncthreads();

    // gather + AND-reduce: thread (c,h) owns words {2h,2h+1} of clause m0+c
    {
        const int c = t >> 1;
        const int h = t & 1;
        const int n = sh_cnt[c];
        const uint16_t* lst = sh_list + c * SLOTS;
        uint64_t a0 = ~0ull, a1 = ~0ull;
        for (int k = 0; k < n; ++k) {
            int d = (int)lst[k];
            const ulonglong2 v =
                *(const ulonglong2*)(litbits + (((size_t)d * B + b) * 4 + 2 * h));
            a0 &= v.x;
            a1 &= v.y;
        }
        res[c * 4 + 2 * h]     = a0;
        res[c * 4 + 2 * h + 1] = a1;
    }
    __syncthreads();

    // expand: 64 clauses x 49 float4 = 3136 consecutive 16B stores (50 KB span)
    {
        float4* outp = (float4*)cmap + ((size_t)b * M + m0) * NF4;
        for (int f = t; f < MT * NF4; f += 128) {
            int c  = f / NF4;
            int q  = f - c * NF4;             // 0..48
            int wd = q >> 4;
            int sh = (q & 15) * 4;
            unsigned nib = (unsigned)((res[c * 4 + wd] >> sh) & 0xFull);
            float4 o;
            o.x = (nib & 1u) ? 1.0f : 0.0f;
            o.y = (nib & 2u) ? 1.0f : 0.0f;
            o.z = (nib & 4u) ? 1.0f : 0.0f;
            o.w = (nib & 8u) ? 1.0f : 0.0f;
            outp[f] = o;
        }
    }

    if (t < MT) {
        // n==0 leaves ~0 garbage above bit 195 -> still correctly "fires"
        uint64_t w = res[t * 4] | res[t * 4 + 1] | res[t * 4 + 2] | res[t * 4 + 3];
        cor[(size_t)b * M + m0 + t] = w ? 1.0f : 0.0f;
    }
}

// ---------------------------------------------------------------------------
// Logits: one block per (b, c); thread k reduces cor[b, c*K+k] * alpha * sign.
// ---------------------------------------------------------------------------
__global__ __launch_bounds__(256) void logits_k(
    const float* __restrict__ cor, const float* __restrict__ alpha,
    float* __restrict__ logits) {
    const int c = blockIdx.x % CC;
    const int b = blockIdx.x / CC;
    const int k = threadIdx.x;  // 0..255 == K
    const float sgn = (k < (K / 2)) ? 1.0f : -1.0f;
    float v = cor[(size_t)b * M + (size_t)c * K + k] * alpha[(size_t)c * K + k] * sgn;
#pragma unroll
    for (int off = 32; off > 0; off >>= 1) v += __shfl_down(v, off, 64);
    __shared__ float sv[4];
    if ((k & 63) == 0) sv[k >> 6] = v;
    __syncthreads();
    if (k == 0) logits[blockIdx.x] = sv[0] + sv[1] + sv[2] + sv[3];
}

// ---------------------------------------------------------------------------
extern "C" void kernel_launch(void* const* d_in, const int* in_sizes, int n_in,
                              void* d_out, int out_size, void* d_ws, size_t ws_size,
                              hipStream_t stream) {
    const float* lit   = (const float*)d_in[0];  // [B, D, L] float32 {0,1}
    const int*   mask  = (const int*)  d_in[1];  // [M, D] bool -> int32
    const float* alpha = (const float*)d_in[2];  // [M]

    float* out    = (float*)d_out;
    float* cmap   = out;                          // [B, M, L]
    float* cor    = out + (size_t)B * M * L;      // [B, M]
    float* logits = cor + (size_t)B * M;          // [B, CC]

    // workspace: 589824 + 10240 + 327680 B < 1 MB
    uint64_t* litbits = (uint64_t*)d_ws;                      // [D][B][4]
    int*      cnt     = (int*)(litbits + (size_t)D * B * 4);  // [M]
    uint16_t* list    = (uint16_t*)(cnt + M);                 // [M][SLOTS]

    prologue_k<<<PACK_BLOCKS + CSR_BLOCKS, 256, 0, stream>>>(
        lit, mask, litbits, cnt, list);

    clause_eval4_k<<<dim3(M / MT, B), 128, 0, stream>>>(
        litbits, cnt, list, cmap, cor);

    logits_k<<<B * CC, 256, 0, stream>>>(cor, alpha, logits);
}

// Round 6
// 101.529 us; speedup vs baseline: 1.0087x; 1.0087x over previous
//
#include <hip/hip_runtime.h>
#include <stdint.h>

#define B  32
#define D  576
#define L  196
#define CC 10
#define K  256
#define M  (CC * K)   // 2560
#define SLOTS 64      // max selected literals per clause (P(Binom(576,.02)>64) ~ 1e-34)
#define NF4 49        // float4 chunks per 196-patch row
#define MT 64         // clause tile per block

#define PACK_BLOCKS ((B * D + 3) / 4)   // 4608 blocks, wave per (b,d)
#define CSR_BLOCKS  ((M + 3) / 4)       // 640 blocks, wave per clause

// ---------------------------------------------------------------------------
// Fused prologue. Blocks [0, PACK_BLOCKS): pack literals over the PATCH axis:
// litbits[(b*D + d)*4 + w], bit (l%64) of word (l/64) = (lit[b][d][l] > 0.5).
// (b-major layout so eval can stage one batch's whole table contiguously.)
// Blocks [PACK_BLOCKS, +CSR_BLOCKS): CSR of selected literal indices/clause.
// ---------------------------------------------------------------------------
__global__ __launch_bounds__(256) void prologue_k(
    const float* __restrict__ lit, const int* __restrict__ mask,
    uint64_t* __restrict__ litbits, int* __restrict__ cnt,
    uint16_t* __restrict__ list) {
    const int lane = threadIdx.x & 63;
    const int wave = threadIdx.x >> 6;

    if (blockIdx.x < PACK_BLOCKS) {
        const int wid = blockIdx.x * 4 + wave;   // [0, B*D)
        if (wid >= B * D) return;
        const int b = wid % B;
        const int d = wid / B;
        const float* base = lit + ((size_t)b * D + d) * L;

        uint64_t w0 = __ballot(base[lane] > 0.5f);
        uint64_t w1 = __ballot(base[64 + lane] > 0.5f);
        uint64_t w2 = __ballot(base[128 + lane] > 0.5f);
        float tail = (lane < 4) ? base[192 + lane] : 0.0f;
        uint64_t w3 = __ballot(tail > 0.5f);

        uint64_t* out = litbits + ((size_t)b * D + d) * 4;
        if (lane == 0) { out[0] = w0; out[1] = w1; out[2] = w2; out[3] = w3; }
    } else {
        const int m = (blockIdx.x - PACK_BLOCKS) * 4 + wave;
        if (m >= M) return;
        const int* row = mask + (size_t)m * D;
        int base = 0;
#pragma unroll
        for (int r = 0; r < 9; ++r) {
            int d = r * 64 + lane;
            bool sel = (row[d] != 0);
            uint64_t bal = __ballot(sel);
            if (sel) {
                int pos = base + __popcll(bal & ((1ull << lane) - 1ull));
                if (pos < SLOTS) list[(size_t)m * SLOTS + pos] = (uint16_t)d;
            }
            base += __popcll(bal);
        }
        if (lane == 0) cnt[m] = (base < SLOTS) ? base : SLOTS;
    }
}

// ---------------------------------------------------------------------------
// Main v5 (fixed): block (mt, b) = batch b, clauses m0..m0+63. 256 threads.
// Phase 1: stage batch b's ENTIRE packed-literal table (18.4 KB) into LDS via
//          1152 independent coalesced uint4 loads (latency fully overlapped),
//          plus the 64 clause lists transposed [slot][clause] (512 uint4 —
//          2 per thread; R5 bug was loading only 256) and counts.
// Phase 2: gather+AND from LDS, 4 threads per clause (thread h owns word h).
//          No global-latency chain anywhere in the loop.
// Phase 3: nibble-expand -> 3136 consecutive float4 stores (one 50 KB span).
// Grid = 40 x 32 = 1280 = 5 blocks/CU; LDS 28.9 KB/block -> exactly 5/CU.
// ---------------------------------------------------------------------------
__global__ __launch_bounds__(256) void clause_eval5_k(
    const uint64_t* __restrict__ litbits, const int* __restrict__ cnt,
    const uint16_t* __restrict__ list, float* __restrict__ cmap,
    float* __restrict__ cor) {
    __shared__ uint64_t lit_s[D * 4];           // 18432 B: [d][word]
    __shared__ uint16_t listT[SLOTS * MT];      // 8192 B: [slot][clause]
    __shared__ uint64_t res[MT * 4];            // 2048 B: [clause][word]
    __shared__ int      sh_cnt[MT];             // 256 B

    const int t  = threadIdx.x;                 // 0..255
    const int m0 = blockIdx.x * MT;
    const int b  = blockIdx.y;

    // ---- stage litbits[b] : 1152 uint4, coalesced, all independent ----
    {
        const uint4* gp = (const uint4*)(litbits + (size_t)b * D * 4);
        uint4* sp = (uint4*)lit_s;
#pragma unroll
        for (int i = 0; i < 4; ++i) sp[t + 256 * i] = gp[t + 256 * i];
        if (t < D * 2 - 1024) sp[1024 + t] = gp[1024 + t];   // 128 tail
    }
    // ---- stage clause lists transposed + counts: 512 uint4, 2/thread ----
    {
        const uint4* lp = (const uint4*)(list + (size_t)m0 * SLOTS);
#pragma unroll
        for (int i = 0; i < 2; ++i) {
            int idx = t + 256 * i;              // 0..511
            uint4 v = lp[idx];
            const uint16_t* e = (const uint16_t*)&v;
            int c  = idx >> 3;                  // clause 0..63
            int s0 = (idx & 7) * 8;             // slot base
#pragma unroll
            for (int j = 0; j < 8; ++j) listT[(s0 + j) * MT + c] = e[j];
        }
        if (t < MT) sh_cnt[t] = cnt[m0 + t];
    }
    __syncthreads();

    // ---- gather + AND from LDS: 4 threads per clause ----
    {
        const int c = t >> 2;
        const int h = t & 3;
        const int n = sh_cnt[c];
        uint64_t a = ~0ull;
        for (int k = 0; k < n; ++k) {
            int d = (int)listT[k * MT + c];
            a &= lit_s[d * 4 + h];
        }
        res[t] = a;   // res[c*4 + h]
    }
    __syncthreads();

    // ---- expand: 64 clauses x 49 float4 = one contiguous 50 KB span ----
    {
        float4* outp = (float4*)cmap + ((size_t)b * M + m0) * NF4;
        for (int f = t; f < MT * NF4; f += 256) {
            int c  = f / NF4;
            int q  = f - c * NF4;               // 0..48
            int wd = q >> 4;
            int sh = (q & 15) * 4;
            unsigned nib = (unsigned)((res[c * 4 + wd] >> sh) & 0xFull);
            float4 o;
            o.x = (nib & 1u) ? 1.0f : 0.0f;
            o.y = (nib & 2u) ? 1.0f : 0.0f;
            o.z = (nib & 4u) ? 1.0f : 0.0f;
            o.w = (nib & 8u) ? 1.0f : 0.0f;
            outp[f] = o;
        }
    }

    if (t < MT) {
        // n==0 leaves ~0 garbage above bit 195 -> mask word3, still "fires"
        uint64_t w = res[t * 4] | res[t * 4 + 1] | res[t * 4 + 2] |
                     (res[t * 4 + 3] & 0xFull);
        cor[(size_t)b * M + m0 + t] = w ? 1.0f : 0.0f;
    }
}

// ---------------------------------------------------------------------------
// Logits: one block per (b, c); thread k reduces cor[b, c*K+k] * alpha * sign.
// ---------------------------------------------------------------------------
__global__ __launch_bounds__(256) void logits_k(
    const float* __restrict__ cor, const float* __restrict__ alpha,
    float* __restrict__ logits) {
    const int c = blockIdx.x % CC;
    const int b = blockIdx.x / CC;
    const int k = threadIdx.x;  // 0..255 == K
    const float sgn = (k < (K / 2)) ? 1.0f : -1.0f;
    float v = cor[(size_t)b * M + (size_t)c * K + k] * alpha[(size_t)c * K + k] * sgn;
#pragma unroll
    for (int off = 32; off > 0; off >>= 1) v += __shfl_down(v, off, 64);
    __shared__ float sv[4];
    if ((k & 63) == 0) sv[k >> 6] = v;
    __syncthreads();
    if (k == 0) logits[blockIdx.x] = sv[0] + sv[1] + sv[2] + sv[3];
}

// ---------------------------------------------------------------------------
extern "C" void kernel_launch(void* const* d_in, const int* in_sizes, int n_in,
                              void* d_out, int out_size, void* d_ws, size_t ws_size,
                              hipStream_t stream) {
    const float* lit   = (const float*)d_in[0];  // [B, D, L] float32 {0,1}
    const int*   mask  = (const int*)  d_in[1];  // [M, D] bool -> int32
    const float* alpha = (const float*)d_in[2];  // [M]

    float* out    = (float*)d_out;
    float* cmap   = out;                          // [B, M, L]
    float* cor    = out + (size_t)B * M * L;      // [B, M]
    float* logits = cor + (size_t)B * M;          // [B, CC]

    // workspace: 589824 + 10240 + 327680 B < 1 MB
    uint64_t* litbits = (uint64_t*)d_ws;                      // [B][D][4]
    int*      cnt     = (int*)(litbits + (size_t)B * D * 4);  // [M]
    uint16_t* list    = (uint16_t*)(cnt + M);                 // [M][SLOTS]

    prologue_k<<<PACK_BLOCKS + CSR_BLOCKS, 256, 0, stream>>>(
        lit, mask, litbits, cnt, list);

    clause_eval5_k<<<dim3(M / MT, B), 256, 0, stream>>>(
        litbits, cnt, list, cmap, cor);

    logits_k<<<B * CC, 256, 0, stream>>>(cor, alpha, logits);
}